// Round 11
// baseline (1102.716 us; speedup 1.0000x reference)
//
#include <hip/hip_runtime.h>
#include <hip/hip_fp8.h>

#define B_ 2048
#define D_ 512
#define V_ 50304
#define NPG 131              // 131 panel-groups x 3 panels x 128 cols = 50304
#define NWG (16 * NPG)       // 2096 = 8 * 262
#define NCOPY 32
#define LOG2E 1.44269504088896340736f
#define LN2 0.69314718055994530942f

typedef __attribute__((ext_vector_type(16))) float f32x16;
typedef __attribute__((ext_vector_type(8))) int v8i;
typedef unsigned char u8;

__device__ inline void gload16(const void* g, void* l) {
  __builtin_amdgcn_global_load_lds((const __attribute__((address_space(1))) void*)g,
                                   (__attribute__((address_space(3))) void*)l, 16, 0, 0);
}

// ---------------- transposing cast fp32 -> fp8 e4m3 (fragment-linear panels) ----------------
// 32-B chunk i = ((p*8 + kc)*2 + h)*128 + c : row/col c of panel p, k = kc*64 + h*32 + [0..32)
__global__ void cast8t_kernel(const float* __restrict__ src, uint4* __restrict__ dst,
                              float scale, int nchunk) {
  int i = blockIdx.x * blockDim.x + threadIdx.x;
  if (i >= nchunk) return;
  int c = i & 127;
  int h = (i >> 7) & 1;
  int kc = (i >> 8) & 7;
  int p = i >> 11;
  const float4* s = (const float4*)(src + (size_t)(p * 128 + c) * 512 + kc * 64 + h * 32);
  union { u8 b[32]; uint4 u[2]; } o;
#pragma unroll
  for (int q = 0; q < 8; ++q) {
    float4 f = s[q];
    o.b[q * 4 + 0] = __hip_fp8_e4m3(f.x * scale).__x;
    o.b[q * 4 + 1] = __hip_fp8_e4m3(f.y * scale).__x;
    o.b[q * 4 + 2] = __hip_fp8_e4m3(f.z * scale).__x;
    o.b[q * 4 + 3] = __hip_fp8_e4m3(f.w * scale).__x;
  }
  dst[2 * i] = o.u[0];
  dst[2 * i + 1] = o.u[1];
}

// ---------------- exact fp32 target logit (one wave per row) ----------------
__global__ void tgt_kernel(const float* __restrict__ sh, const float* __restrict__ sc,
                           const int* __restrict__ targets, float* __restrict__ tgt_out) {
  int gid = blockIdx.x * blockDim.x + threadIdx.x;
  int w = gid >> 6, lane = gid & 63;
  if (w >= B_) return;
  int tgt = targets[w];
  const float4* a = (const float4*)(sh + (size_t)w * D_);
  const float4* b = (const float4*)(sc + (size_t)tgt * D_);
  float acc = 0.f;
#pragma unroll
  for (int i = 0; i < 2; ++i) {
    float4 x = a[lane + i * 64], y = b[lane + i * 64];
    acc += x.x * y.x + x.y * y.y + x.z * y.z + x.w * y.w;
  }
#pragma unroll
  for (int off = 1; off < 64; off <<= 1) acc += __shfl_xor(acc, off);
  if (lane == 0) tgt_out[w] = acc;
}

// ---------------- fused dual-GEMM, MX-fp8 32x32x64, dual-mat waves, 3 panels/block ----------------
// Wave (wr,wc) computes BOTH student and teacher for its 64x64 quadrant: the (s,t)
// logit pair lives in one thread -> register-only epilogue, no LDS exchange.
__global__ __launch_bounds__(256, 2) void lce_main(
    const u8* __restrict__ SH8t, const u8* __restrict__ TH8t,
    const u8* __restrict__ SC8t, const u8* __restrict__ TC8t,
    float* __restrict__ stats32) {
  __shared__ __align__(16) u8 smem[2][2][8192];  // [buf][mat][hi*4096 + col*32] : 32 KB

  const int tid = threadIdx.x;
  const int lane = tid & 63, w = tid >> 6;
  const int wr = w >> 1, wc = w & 1;
  const int l5 = lane & 31, hi = lane >> 5;

  // XCD-aware bijective swizzle: 2096 = 8 * 262
  const int hw = blockIdx.x;
  const int lid = (hw & 7) * (NWG / 8) + (hw >> 3);
  const int row0 = (lid & 15) * 128;
  const int pg = lid >> 4;      // 0..130
  const int jcopy = (hw & 7) * 4 + (pg & 3);
  float* stats = stats32 + (size_t)jcopy * B_ * 3;

  // A bases (fragment-linear hidden panels): per-lane 32-B frag, 1-KB coalesced segments
  const int pA = lid & 15;
  const u8* gAs = SH8t + (size_t)pA * 65536 + hi * 4096 + wr * 2048 + l5 * 32;
  const u8* gAt = TH8t + (size_t)pA * 65536 + hi * 4096 + wr * 2048 + l5 * 32;
  // B stage sources: pure linear copy per (panel, kc) 8-KB chunk
  const u8* gBs = SC8t + tid * 16;
  const u8* gBt = TC8t + tid * 16;
  // B fragment LDS byte base
  const int bbase = hi * 4096 + wc * 2048 + l5 * 32;

  f32x16 accS[2][2], accT[2][2];
  v8i aS[2], aT[2];

#define STAGE(buf, poff)                                                      \
  {                                                                           \
    gload16(gBs + (poff), &smem[buf][0][tid * 16]);                           \
    gload16(gBs + (poff) + 4096, &smem[buf][0][4096 + tid * 16]);             \
    gload16(gBt + (poff), &smem[buf][1][tid * 16]);                           \
    gload16(gBt + (poff) + 4096, &smem[buf][1][4096 + tid * 16]);             \
  }

#define LOADA(pq, kc)                                                         \
  {                                                                           \
    aS[0] = *(const v8i*)(gAs + (kc) * 8192);                                 \
    aS[1] = *(const v8i*)(gAs + (kc) * 8192 + 1024);                          \
    aT[0] = *(const v8i*)(gAt + (kc) * 8192);                                 \
    aT[1] = *(const v8i*)(gAt + (kc) * 8192 + 1024);                          \
  }

  const float inv = 1.0f / 256.0f;  // acc = logit * 256 * LOG2E

  // prologue: stage panel0 kc0
  STAGE(0, (size_t)(pg * 3) * 65536);

  for (int pp = 0; pp < 3; ++pp) {
    const size_t pbase = (size_t)(pg * 3 + pp) * 65536;
#pragma unroll
    for (int mi = 0; mi < 2; ++mi)
#pragma unroll
      for (int ni = 0; ni < 2; ++ni)
#pragma unroll
        for (int e = 0; e < 16; ++e) { accS[mi][ni][e] = 0.f; accT[mi][ni][e] = 0.f; }

#pragma unroll
    for (int kc = 0; kc < 8; ++kc) {
      const int buf = kc & 1;
      LOADA(pp, kc);
      if (kc < 7) {
        STAGE(buf ^ 1, pbase + (kc + 1) * 8192);
        asm volatile("s_waitcnt vmcnt(12)\n\ts_barrier" ::: "memory");
      } else if (pp < 2) {
        STAGE(0, pbase + 65536);  // next panel's kc0 into buf0
        asm volatile("s_waitcnt vmcnt(12)\n\ts_barrier" ::: "memory");
      } else {
        asm volatile("s_waitcnt vmcnt(8)\n\ts_barrier" ::: "memory");
      }

      v8i bS[2], bT[2];
#pragma unroll
      for (int ni = 0; ni < 2; ++ni) {
        bS[ni] = *(const v8i*)&smem[buf][0][bbase + ni * 1024];
        bT[ni] = *(const v8i*)&smem[buf][1][bbase + ni * 1024];
      }
#pragma unroll
      for (int mi = 0; mi < 2; ++mi)
#pragma unroll
        for (int ni = 0; ni < 2; ++ni) {
          accS[mi][ni] = __builtin_amdgcn_mfma_scale_f32_32x32x64_f8f6f4(
              aS[mi], bS[ni], accS[mi][ni], 0, 0, 0, 127, 0, 127);
          accT[mi][ni] = __builtin_amdgcn_mfma_scale_f32_32x32x64_f8f6f4(
              aT[mi], bT[ni], accT[mi][ni], 0, 0, 0, 127, 0, 127);
        }
      asm volatile("s_barrier" ::: "memory");
    }

    // ---- per-panel register-only epilogue (overlaps next panel's in-flight stage) ----
#pragma unroll
    for (int mi = 0; mi < 2; ++mi) {
#pragma unroll
      for (int reg = 0; reg < 16; ++reg) {
        float ss = 0.f, st = 0.f, at = 0.f;
#pragma unroll
        for (int ni = 0; ni < 2; ++ni) {
          float sv = accS[mi][ni][reg] * inv;
          float tv = accT[mi][ni][reg] * inv;
          float es = __builtin_amdgcn_exp2f(sv);
          float et = __builtin_amdgcn_exp2f(tv);
          ss += es;
          st += et;
          at += et * (tv - sv);
        }
#pragma unroll
        for (int off = 1; off < 32; off <<= 1) {
          ss += __shfl_xor(ss, off);
          st += __shfl_xor(st, off);
          at += __shfl_xor(at, off);
        }
        if (l5 == 0) {
          int row = row0 + wr * 64 + mi * 32 + (reg & 3) + 8 * (reg >> 2) + 4 * hi;
          atomicAdd(&stats[(size_t)row * 3 + 0], ss);
          atomicAdd(&stats[(size_t)row * 3 + 1], st);
          atomicAdd(&stats[(size_t)row * 3 + 2], at);
        }
      }
    }
  }
}

// ---------------- finalize: sum spread copies, per-row loss + global sum ----------------
__global__ void finalize(const float* __restrict__ stats32, const float* __restrict__ tgt,
                         const float* __restrict__ cec, const float* __restrict__ klc,
                         float* __restrict__ out) {
  __shared__ float red[16];
  int tid = threadIdx.x;  // 1024 threads
  float acc = 0.f;
  for (int r = tid; r < B_; r += 1024) {
    float ss = 0.f, st = 0.f, at = 0.f;
#pragma unroll
    for (int j = 0; j < NCOPY; ++j) {
      const float* s = stats32 + ((size_t)j * B_ + r) * 3;
      ss += s[0]; st += s[1]; at += s[2];
    }
    float s_lse = LN2 * __builtin_amdgcn_logf(ss);
    float t_lse = LN2 * __builtin_amdgcn_logf(st);
    float kl = s_lse - t_lse + LN2 * at / st;
    float ce = s_lse - tgt[r];
    acc += cec[r] * ce + klc[r] * kl;
  }
#pragma unroll
  for (int off = 1; off < 64; off <<= 1) acc += __shfl_xor(acc, off);
  if ((tid & 63) == 0) red[tid >> 6] = acc;
  __syncthreads();
  if (tid == 0) {
    float s = 0.f;
#pragma unroll
    for (int i = 0; i < 16; ++i) s += red[i];
    out[0] = s;
  }
}

extern "C" void kernel_launch(void* const* d_in, const int* in_sizes, int n_in,
                              void* d_out, int out_size, void* d_ws, size_t ws_size,
                              hipStream_t stream) {
  const float* sh = (const float*)d_in[0];
  const float* sc = (const float*)d_in[1];
  const float* th = (const float*)d_in[2];
  const float* tc = (const float*)d_in[3];
  const float* cec = (const float*)d_in[4];
  const float* klc = (const float*)d_in[5];
  const int* targets = (const int*)d_in[6];
  float* out = (float*)d_out;

  char* ws = (char*)d_ws;
  u8* SC8t = (u8*)ws;                               // 25,755,648 (393 panels)
  u8* TC8t = SC8t + (size_t)V_ * D_;                // 25,755,648
  u8* SH8t = TC8t + (size_t)V_ * D_;                // 1,048,576 (16 panels)
  u8* TH8t = SH8t + (size_t)B_ * D_;                // 1,048,576
  float* stats32 = (float*)(TH8t + (size_t)B_ * D_); // 786,432 B: [32][2048][3]
  float* tgt = stats32 + (size_t)NCOPY * B_ * 3;    // 8 KB
  // total ~54.4 MB, within confirmed ws_size >= 55.7 MB

  hipMemsetAsync(stats32, 0, (size_t)NCOPY * B_ * 3 * sizeof(float), stream);
  const float hscale = 16.0f * LOG2E;
  const float cscale = 16.0f;
  const int ncC = V_ * D_ / 32;  // 804,864
  const int ncH = B_ * D_ / 32;  // 32,768
  cast8t_kernel<<<(ncC + 255) / 256, 256, 0, stream>>>(sc, (uint4*)SC8t, cscale, ncC);
  cast8t_kernel<<<(ncC + 255) / 256, 256, 0, stream>>>(tc, (uint4*)TC8t, cscale, ncC);
  cast8t_kernel<<<(ncH + 255) / 256, 256, 0, stream>>>(sh, (uint4*)SH8t, hscale, ncH);
  cast8t_kernel<<<(ncH + 255) / 256, 256, 0, stream>>>(th, (uint4*)TH8t, hscale, ncH);
  tgt_kernel<<<512, 256, 0, stream>>>(sh, sc, targets, tgt);

  lce_main<<<NWG, 256, 0, stream>>>(SH8t, TH8t, SC8t, TC8t, stats32);
  finalize<<<1, 1024, 0, stream>>>(stats32, tgt, cec, klc, out);
}

// Round 12
// 272.612 us; speedup vs baseline: 4.0450x; 4.0450x over previous
//
#include <hip/hip_runtime.h>
#include <hip/hip_fp8.h>

#define B_ 2048
#define D_ 512
#define V_ 50304
#define NROWB 16            // 2048 / 128
#define NCOLB 393           // 50304 / 128
#define NWG (NROWB * NCOLB) // 6288 = 8 * 786
#define NCOPY 32
#define LOG2E 1.44269504088896340736f
#define LN2 0.69314718055994530942f

typedef __attribute__((ext_vector_type(4))) float f32x4;
typedef __attribute__((ext_vector_type(2))) unsigned long ulx2;
typedef __attribute__((ext_vector_type(8))) int v8i;
typedef unsigned char u8;

__device__ inline void gload16(const void* g, void* l) {
  __builtin_amdgcn_global_load_lds((const __attribute__((address_space(1))) void*)g,
                                   (__attribute__((address_space(3))) void*)l, 16, 0, 0);
}

__device__ inline unsigned f2bf(float f) {
  unsigned u = __float_as_uint(f);
  u += 0x7fffu + ((u >> 16) & 1u);
  return u >> 16;
}

// ---------------- coalesced transposing cast fp32 -> fp8 e4m3 (both classifiers) ----------------
// One block per 128x128 slab (p, kk). Reads: each wave covers 2 full 512-B source rows
// (coalesced). LDS 128x128 fp8 tile with XOR-swizzled 16-B slots. Writes: 1-KB contiguous.
// Output layout (matches lce STAGE/ds_read): slab*16384 + jslot*2048 + c*16,
// where slab = p*4 + kk, jslot = k-16-group (k = kk*128 + jslot*16 + [0..16)), c = vocab row.
__global__ __launch_bounds__(256) void castT_kernel(const float* __restrict__ SC,
                                                    const float* __restrict__ TC,
                                                    u8* __restrict__ SC8t, u8* __restrict__ TC8t,
                                                    float scale) {
  __shared__ __align__(16) u8 lt[16384];
  const int slab = blockIdx.x;       // 0..3143
  const int half = slab >= 1572;     // 0 = SC, 1 = TC
  const int s2 = half ? slab - 1572 : slab;
  const int p = s2 >> 2, kk = s2 & 3;
  const float* src = (half ? TC : SC) + (size_t)p * 128 * 512 + kk * 128;
  u8* dst = (half ? TC8t : SC8t) + (size_t)s2 * 16384;

  const int t = threadIdx.x;
  const int rlo = t >> 5;            // row within 8-row group
  const int c16 = t & 31;            // float4 index within row (32 x 4 = 128 floats)
  const int jslot = c16 >> 2, wi = c16 & 3;

#pragma unroll
  for (int i = 0; i < 16; ++i) {
    const int row = i * 8 + rlo;
    float4 f = *(const float4*)(src + (size_t)row * 512 + c16 * 4);
    union { u8 b[4]; uint u; } o;
    o.b[0] = __hip_fp8_e4m3(f.x * scale).__x;
    o.b[1] = __hip_fp8_e4m3(f.y * scale).__x;
    o.b[2] = __hip_fp8_e4m3(f.z * scale).__x;
    o.b[3] = __hip_fp8_e4m3(f.w * scale).__x;
    *(uint*)&lt[row * 128 + ((jslot ^ (row & 7)) * 16) + wi * 4] = o.u;
  }
  __syncthreads();
#pragma unroll
  for (int i = 0; i < 4; ++i) {
    const int chunk = i * 256 + t;   // 0..1023
    const int js = chunk >> 7, c = chunk & 127;
    uint4 v = *(const uint4*)&lt[c * 128 + ((js ^ (c & 7)) * 16)];
    *(uint4*)(dst + js * 2048 + c * 16) = v;
  }
}

// ---------------- plain cast fp32 -> fp8 e4m3 (hidden, row-major) ----------------
__global__ void cast8_kernel(const float* __restrict__ src, uint2* __restrict__ dst,
                             float scale, int n8) {
  int i = blockIdx.x * blockDim.x + threadIdx.x;
  int stride = gridDim.x * blockDim.x;
  const float4* s4 = (const float4*)src;
  for (; i < n8; i += stride) {
    float4 a = s4[2 * i], b = s4[2 * i + 1];
    union { u8 c[8]; uint2 u; } p;
    p.c[0] = __hip_fp8_e4m3(a.x * scale).__x;
    p.c[1] = __hip_fp8_e4m3(a.y * scale).__x;
    p.c[2] = __hip_fp8_e4m3(a.z * scale).__x;
    p.c[3] = __hip_fp8_e4m3(a.w * scale).__x;
    p.c[4] = __hip_fp8_e4m3(b.x * scale).__x;
    p.c[5] = __hip_fp8_e4m3(b.y * scale).__x;
    p.c[6] = __hip_fp8_e4m3(b.z * scale).__x;
    p.c[7] = __hip_fp8_e4m3(b.w * scale).__x;
    dst[i] = p.u;
  }
}

// ---------------- exact fp32 target logit (one wave per row) ----------------
__global__ void tgt_kernel(const float* __restrict__ sh, const float* __restrict__ sc,
                           const int* __restrict__ targets, float* __restrict__ tgt_out) {
  int gid = blockIdx.x * blockDim.x + threadIdx.x;
  int w = gid >> 6, lane = gid & 63;
  if (w >= B_) return;
  int tgt = targets[w];
  const float4* a = (const float4*)(sh + (size_t)w * D_);
  const float4* b = (const float4*)(sc + (size_t)tgt * D_);
  float acc = 0.f;
#pragma unroll
  for (int i = 0; i < 2; ++i) {
    float4 x = a[lane + i * 64], y = b[lane + i * 64];
    acc += x.x * y.x + x.y * y.y + x.z * y.z + x.w * y.w;
  }
#pragma unroll
  for (int off = 1; off < 64; off <<= 1) acc += __shfl_xor(acc, off);
  if (lane == 0) tgt_out[w] = acc;
}

// ---------------- fused dual-GEMM, MX-fp8 K=128, S/T wave split (r6, verbatim) ----------------
__global__ __launch_bounds__(256, 2) void lce_main(
    const u8* __restrict__ SH8, const u8* __restrict__ TH8,
    const u8* __restrict__ SC8t, const u8* __restrict__ TC8t,
    float* __restrict__ stats32) {
  __shared__ __align__(16) u8 smem[2][2][16384];

  const int tid = threadIdx.x;
  const int lane = tid & 63, w = tid >> 6;
  const int mat = w & 1;        // 0 = student, 1 = teacher
  const int wr = w >> 1;        // row half (64 rows)
  const int rA = lane & 15;
  const int kg = lane >> 4;     // 0..3

  // XCD-aware bijective swizzle: 6288 = 8 * 786; lid = xcd*786 + seq
  int hw = blockIdx.x;
  int lid = (hw & 7) * 786 + (hw >> 3);
  const int row0 = (lid & 15) * 128;
  const int p = lid >> 4;       // col panel index
  const int jcopy = (hw & 7) * 4 + ((lid >> 4) & 3);
  float* stats = stats32 + (size_t)jcopy * B_ * 3;

  const u8* gBs = SC8t + (size_t)p * 65536 + tid * 16;
  const u8* gBt = TC8t + (size_t)p * 65536 + tid * 16;
  const u8* gA = (mat ? TH8 : SH8) + (size_t)(row0 + wr * 64 + rA) * D_ + kg * 32;

  f32x4 acc[4][8];
#pragma unroll
  for (int i = 0; i < 4; ++i)
#pragma unroll
    for (int j = 0; j < 8; ++j) acc[i][j] = (f32x4){0.f, 0.f, 0.f, 0.f};

  v8i av[2][4];

#define STAGE(buf, kk)                                                        \
  {                                                                           \
    _Pragma("unroll") for (int mt = 0; mt < 2; ++mt) {                        \
      _Pragma("unroll") for (int r = 0; r < 4; ++r) {                         \
        gload16((mt ? gBt : gBs) + (kk) * 16384 + r * 4096,                   \
                &smem[buf][mt][r * 4096 + tid * 16]);                         \
      }                                                                       \
    }                                                                         \
  }

#define LOADA(buf, kk)                                                        \
  {                                                                           \
    _Pragma("unroll") for (int mi = 0; mi < 4; ++mi) {                        \
      av[buf][mi] = *(const v8i*)(gA + (size_t)(mi * 16) * D_ + (kk) * 128);  \
    }                                                                         \
  }

  STAGE(0, 0);
  LOADA(0, 0);

#pragma unroll
  for (int kk = 0; kk < 4; ++kk) {
    const int par = kk & 1;
    if (kk < 3) {
      STAGE(par ^ 1, kk + 1);
      LOADA(par ^ 1, kk + 1);
    }
    if (kk < 3)
      asm volatile("s_waitcnt vmcnt(16)\n\ts_barrier" ::: "memory");
    else
      asm volatile("s_waitcnt vmcnt(8)\n\ts_barrier" ::: "memory");

    __builtin_amdgcn_s_setprio(1);
#pragma unroll
    for (int ni = 0; ni < 8; ++ni) {
      const u8* bp = &smem[par][mat][(2 * kg) * 2048 + (ni * 16 + rA) * 16];
      union { struct { ulx2 lo, hi; } s; v8i v; } ub;
      ub.s.lo = *(const ulx2*)bp;
      ub.s.hi = *(const ulx2*)(bp + 2048);
#pragma unroll
      for (int mi = 0; mi < 4; ++mi)
        acc[mi][ni] = __builtin_amdgcn_mfma_scale_f32_16x16x128_f8f6f4(
            av[par][mi], ub.v, acc[mi][ni], 0, 0, 0, 127, 0, 127);
    }
    __builtin_amdgcn_s_setprio(0);
    asm volatile("s_barrier" ::: "memory");
  }

  // ---------------- epilogue ----------------
  const float inv = 1.0f / 256.0f;  // acc = logit * 256 * LOG2E
  float2* exch = (float2*)smem;

  if (mat == 0) {
#pragma unroll
    for (int mi = 0; mi < 4; ++mi)
#pragma unroll
      for (int ni = 0; ni < 8; ++ni)
#pragma unroll
        for (int rp = 0; rp < 2; ++rp) {
          float2 v = make_float2(acc[mi][ni][2 * rp] * inv, acc[mi][ni][2 * rp + 1] * inv);
          exch[(size_t)((((wr * 4 + mi) * 8 + ni) * 2 + rp) * 64 + lane)] = v;
        }
  }
  asm volatile("s_waitcnt lgkmcnt(0)\n\ts_barrier" ::: "memory");

  if (mat == 0) {
#pragma unroll
    for (int mi = 0; mi < 4; ++mi) {
      float ssr[4] = {0.f, 0.f, 0.f, 0.f};
#pragma unroll
      for (int ni = 0; ni < 8; ++ni)
#pragma unroll
        for (int reg = 0; reg < 4; ++reg)
          ssr[reg] += __builtin_amdgcn_exp2f(acc[mi][ni][reg] * inv);
#pragma unroll
      for (int reg = 0; reg < 4; ++reg) {
        float v = ssr[reg];
#pragma unroll
        for (int off = 1; off < 16; off <<= 1) v += __shfl_xor(v, off);
        if (rA == 0)
          atomicAdd(&stats[(size_t)(row0 + wr * 64 + mi * 16 + kg * 4 + reg) * 3 + 0], v);
      }
    }
  } else {
#pragma unroll
    for (int mi = 0; mi < 4; ++mi) {
      float str[4] = {0.f, 0.f, 0.f, 0.f};
      float atr[4] = {0.f, 0.f, 0.f, 0.f};
#pragma unroll
      for (int ni = 0; ni < 8; ++ni)
#pragma unroll
        for (int rp = 0; rp < 2; ++rp) {
          float2 sv = exch[(size_t)((((wr * 4 + mi) * 8 + ni) * 2 + rp) * 64 + lane)];
          float tv0 = acc[mi][ni][2 * rp] * inv;
          float tv1 = acc[mi][ni][2 * rp + 1] * inv;
          float et0 = __builtin_amdgcn_exp2f(tv0);
          float et1 = __builtin_amdgcn_exp2f(tv1);
          str[2 * rp] += et0;
          str[2 * rp + 1] += et1;
          atr[2 * rp] += et0 * (tv0 - sv.x);
          atr[2 * rp + 1] += et1 * (tv1 - sv.y);
        }
#pragma unroll
      for (int reg = 0; reg < 4; ++reg) {
        float v = str[reg], u = atr[reg];
#pragma unroll
        for (int off = 1; off < 16; off <<= 1) {
          v += __shfl_xor(v, off);
          u += __shfl_xor(u, off);
        }
        if (rA == 0) {
          size_t r = (size_t)(row0 + wr * 64 + mi * 16 + kg * 4 + reg) * 3;
          atomicAdd(&stats[r + 1], v);
          atomicAdd(&stats[r + 2], u);
        }
      }
    }
  }
}

// ---------------- finalize stage 1: per-row loss (parallel) ----------------
__global__ void finalize1(const float* __restrict__ stats32, const float* __restrict__ tgt,
                          const float* __restrict__ cec, const float* __restrict__ klc,
                          float* __restrict__ rowvals) {
  int r = blockIdx.x * blockDim.x + threadIdx.x;
  if (r >= B_) return;
  float ss = 0.f, st = 0.f, at = 0.f;
#pragma unroll
  for (int j = 0; j < NCOPY; ++j) {
    const float* s = stats32 + ((size_t)j * B_ + r) * 3;
    ss += s[0]; st += s[1]; at += s[2];
  }
  float s_lse = LN2 * __builtin_amdgcn_logf(ss);
  float t_lse = LN2 * __builtin_amdgcn_logf(st);
  float kl = s_lse - t_lse + LN2 * at / st;
  float ce = s_lse - tgt[r];
  rowvals[r] = cec[r] * ce + klc[r] * kl;
}

// ---------------- finalize stage 2: global sum ----------------
__global__ void finalize2(const float* __restrict__ rowvals, float* __restrict__ out) {
  __shared__ float red[4];
  int tid = threadIdx.x;  // 256 threads
  float a = 0.f;
  for (int i = tid; i < B_; i += 256) a += rowvals[i];
#pragma unroll
  for (int off = 1; off < 64; off <<= 1) a += __shfl_xor(a, off);
  if ((tid & 63) == 0) red[tid >> 6] = a;
  __syncthreads();
  if (tid == 0) out[0] = red[0] + red[1] + red[2] + red[3];
}

extern "C" void kernel_launch(void* const* d_in, const int* in_sizes, int n_in,
                              void* d_out, int out_size, void* d_ws, size_t ws_size,
                              hipStream_t stream) {
  const float* sh = (const float*)d_in[0];
  const float* sc = (const float*)d_in[1];
  const float* th = (const float*)d_in[2];
  const float* tc = (const float*)d_in[3];
  const float* cec = (const float*)d_in[4];
  const float* klc = (const float*)d_in[5];
  const int* targets = (const int*)d_in[6];
  float* out = (float*)d_out;

  char* ws = (char*)d_ws;
  u8* SC8t = (u8*)ws;                               // 25,755,648 (transposed)
  u8* TC8t = SC8t + (size_t)V_ * D_;                // 25,755,648 (transposed)
  u8* SH8 = TC8t + (size_t)V_ * D_;                 // 1,048,576 (row-major)
  u8* TH8 = SH8 + (size_t)B_ * D_;                  // 1,048,576 (row-major)
  float* stats32 = (float*)(TH8 + (size_t)B_ * D_); // 786,432 B: [32][2048][3]
  float* tgt = stats32 + (size_t)NCOPY * B_ * 3;    // 8 KB
  float* rowvals = tgt + B_;                        // 8 KB
  // total ~54.4 MB, within confirmed ws_size >= 55.7 MB

  hipMemsetAsync(stats32, 0, (size_t)NCOPY * B_ * 3 * sizeof(float), stream);
  const float hscale = 16.0f * LOG2E;
  const float cscale = 16.0f;
  castT_kernel<<<2 * NCOLB * 4, 256, 0, stream>>>(sc, tc, SC8t, TC8t, cscale);
  cast8_kernel<<<256, 256, 0, stream>>>(sh, (uint2*)SH8, hscale, B_ * D_ / 8);
  cast8_kernel<<<256, 256, 0, stream>>>(th, (uint2*)TH8, hscale, B_ * D_ / 8);
  tgt_kernel<<<512, 256, 0, stream>>>(sh, sc, targets, tgt);

  lce_main<<<NWG, 256, 0, stream>>>(SH8, TH8, SC8t, TC8t, stats32);
  finalize1<<<16, 128, 0, stream>>>(stats32, tgt, cec, klc, rowvals);
  finalize2<<<1, 256, 0, stream>>>(rowvals, out);
}